// Round 4
// baseline (1336.578 us; speedup 1.0000x reference)
//
#include <hip/hip_runtime.h>

#define S_LEN 2048
#define DHEAD 64
#define BATCH 4
#define HEADS 16
#define NTHR 256            // 4 independent waves per block
#define NCHUNK 128          // 2048 keys / 16 keys per chunk
#define NBLK 2048           // (4*16*2048/16 rows-per-wave) / 4 waves-per-block
#define NEG_BIG (-1e9f)

typedef _Float16 half4v __attribute__((ext_vector_type(4)));
typedef _Float16 half8v __attribute__((ext_vector_type(8)));
typedef float floatx4 __attribute__((ext_vector_type(4)));

__device__ __forceinline__ half8v cvt8(float4 a, float4 b) {
    half8v h;
    h[0] = (_Float16)a.x; h[1] = (_Float16)a.y; h[2] = (_Float16)a.z; h[3] = (_Float16)a.w;
    h[4] = (_Float16)b.x; h[5] = (_Float16)b.y; h[6] = (_Float16)b.z; h[7] = (_Float16)b.w;
    return h;
}
__device__ __forceinline__ half8v cvt8s(float4 a, float4 b, float s) {
    half8v h;
    h[0] = (_Float16)(a.x * s); h[1] = (_Float16)(a.y * s); h[2] = (_Float16)(a.z * s); h[3] = (_Float16)(a.w * s);
    h[4] = (_Float16)(b.x * s); h[5] = (_Float16)(b.y * s); h[6] = (_Float16)(b.z * s); h[7] = (_Float16)(b.w * s);
    return h;
}

__global__ __launch_bounds__(NTHR, 6)
void attn_flash(const float* __restrict__ qg, const float* __restrict__ kg,
                const float* __restrict__ vg, const int* __restrict__ maskg,
                float* __restrict__ outg, float* __restrict__ attng)
{
    // per-wave private 16x16 p-tile, padded row stride 20 f16 (40 B) -> ~2-way banks max
    __shared__ _Float16 pt[4 * 16 * 20];

    const int tid  = threadIdx.x;
    const int lane = tid & 63;
    const int w    = tid >> 6;
    const int c    = lane & 15;
    const int g    = lane >> 4;

    // XCD swizzle: consecutive logical blocks (same head) land on the same XCD
    const int rawb = blockIdx.x;
    const int lb   = (rawb & 7) * (NBLK / 8) + (rawb >> 3);
    const int gw   = lb * 4 + w;        // global wave id: owns 16 q-rows
    const int bh   = gw >> 7;           // 128 wave-slots per (b,h)
    const int slot = gw & 127;
    const int q0   = slot << 4;
    const int b    = bh >> 4;           // HEADS = 16

    const float* qp = qg + (size_t)bh * S_LEN * DHEAD;
    const float* kp = kg + (size_t)bh * S_LEN * DHEAD;
    const float* vp = vg + (size_t)bh * S_LEN * DHEAD;
    const int* mrow0 = maskg + (size_t)b * S_LEN * S_LEN + (size_t)(q0 + g * 4) * S_LEN + c;
    float* outp  = outg  + (size_t)bh * S_LEN * DHEAD;
    float* arow0 = attng + (size_t)bh * S_LEN * S_LEN + (size_t)(q0 + g * 4) * S_LEN + c;

    // ---- Q A-frags (f16, pre-scaled by 1/TEMPERATURE), kept across both passes ----
    // A-frag (16x16x32): row = lane&15, k(d) = (lane>>4)*8 + j
    half8v qf0, qf1;
    {
        const float* qb = qp + (size_t)(q0 + c) * DHEAD + g * 8;
        qf0 = cvt8s(*(const float4*)qb,        *(const float4*)(qb + 4),  0.125f);
        qf1 = cvt8s(*(const float4*)(qb + 32), *(const float4*)(qb + 36), 0.125f);
    }

    // ================= pass 1: online (m, z) — no stores, no barriers =================
    float m0 = -3e38f, m1 = -3e38f, m2 = -3e38f, m3 = -3e38f;
    float z0 = 0.f, z1 = 0.f, z2 = 0.f, z3 = 0.f;
    {
        const float* kb = kp + (size_t)c * DHEAD + g * 8;  // B-frag: col=key(c), k=g*8+j
        const int*   mb = mrow0;
        #pragma unroll 2
        for (int t = 0; t < NCHUNK; ++t) {
            half8v kf0 = cvt8(*(const float4*)kb,        *(const float4*)(kb + 4));
            half8v kf1 = cvt8(*(const float4*)(kb + 32), *(const float4*)(kb + 36));
            floatx4 acc = {0.f, 0.f, 0.f, 0.f};
            acc = __builtin_amdgcn_mfma_f32_16x16x32_f16(qf0, kf0, acc, 0, 0, 0);
            acc = __builtin_amdgcn_mfma_f32_16x16x32_f16(qf1, kf1, acc, 0, 0, 0);
            const int k0 = mb[0], k1 = mb[S_LEN], k2 = mb[2 * S_LEN], k3 = mb[3 * S_LEN];
            float x, mn;
            x = k0 ? acc[0] : NEG_BIG; mn = fmaxf(m0, x); z0 = z0 * __expf(m0 - mn) + __expf(x - mn); m0 = mn;
            x = k1 ? acc[1] : NEG_BIG; mn = fmaxf(m1, x); z1 = z1 * __expf(m1 - mn) + __expf(x - mn); m1 = mn;
            x = k2 ? acc[2] : NEG_BIG; mn = fmaxf(m2, x); z2 = z2 * __expf(m2 - mn) + __expf(x - mn); m2 = mn;
            x = k3 ? acc[3] : NEG_BIG; mn = fmaxf(m3, x); z3 = z3 * __expf(m3 - mn) + __expf(x - mn); m3 = mn;
            kb += 16 * DHEAD;
            mb += 16;
        }
    }
    // merge (m,z) across the 16 c-lanes; row-slots (g*4+i) already match pass-2 C-frags
    #pragma unroll
    for (int off = 1; off <= 8; off <<= 1) {
        float mm, zz, mn;
        mm = __shfl_xor(m0, off); zz = __shfl_xor(z0, off);
        mn = fmaxf(m0, mm); z0 = z0 * __expf(m0 - mn) + zz * __expf(mm - mn); m0 = mn;
        mm = __shfl_xor(m1, off); zz = __shfl_xor(z1, off);
        mn = fmaxf(m1, mm); z1 = z1 * __expf(m1 - mn) + zz * __expf(mm - mn); m1 = mn;
        mm = __shfl_xor(m2, off); zz = __shfl_xor(z2, off);
        mn = fmaxf(m2, mm); z2 = z2 * __expf(m2 - mn) + zz * __expf(mm - mn); m2 = mn;
        mm = __shfl_xor(m3, off); zz = __shfl_xor(z3, off);
        mn = fmaxf(m3, mm); z3 = z3 * __expf(m3 - mn) + zz * __expf(mm - mn); m3 = mn;
    }
    const float r0 = 1.f / z0, r1 = 1.f / z1, r2 = 1.f / z2, r3 = 1.f / z3;

    // ================= pass 2: p, attn store, PV — no barriers =================
    floatx4 o[4] = {{0.f,0.f,0.f,0.f},{0.f,0.f,0.f,0.f},{0.f,0.f,0.f,0.f},{0.f,0.f,0.f,0.f}};
    _Float16* myp = &pt[w * 320];
    {
        const float* kb = kp + (size_t)c * DHEAD + g * 8;
        const float* vb = vp + (size_t)(g * 4) * DHEAD + c;   // V[k=g*4+j][d=n*16+c]
        const int*   mb = mrow0;
        float*       ab = arow0;
        for (int t = 0; t < NCHUNK; ++t) {
            half8v kf0 = cvt8(*(const float4*)kb,        *(const float4*)(kb + 4));
            half8v kf1 = cvt8(*(const float4*)(kb + 32), *(const float4*)(kb + 36));
            floatx4 acc = {0.f, 0.f, 0.f, 0.f};
            acc = __builtin_amdgcn_mfma_f32_16x16x32_f16(qf0, kf0, acc, 0, 0, 0);
            acc = __builtin_amdgcn_mfma_f32_16x16x32_f16(qf1, kf1, acc, 0, 0, 0);
            const int k0 = mb[0], k1 = mb[S_LEN], k2 = mb[2 * S_LEN], k3 = mb[3 * S_LEN];
            const float x0 = k0 ? acc[0] : NEG_BIG;
            const float x1 = k1 ? acc[1] : NEG_BIG;
            const float x2 = k2 ? acc[2] : NEG_BIG;
            const float x3 = k3 ? acc[3] : NEG_BIG;
            const float p0 = __expf(x0 - m0) * r0;
            const float p1 = __expf(x1 - m1) * r1;
            const float p2 = __expf(x2 - m2) * r2;
            const float p3 = __expf(x3 - m3) * r3;
            // attn store: f32, 64B-chunk coalesced across the 16 c-lanes
            ab[0] = p0; ab[S_LEN] = p1; ab[2 * S_LEN] = p2; ab[3 * S_LEN] = p3;
            // p -> per-wave LDS tile (intra-wave transpose for the PV A-frag)
            myp[(g * 4 + 0) * 20 + c] = (_Float16)p0;
            myp[(g * 4 + 1) * 20 + c] = (_Float16)p1;
            myp[(g * 4 + 2) * 20 + c] = (_Float16)p2;
            myp[(g * 4 + 3) * 20 + c] = (_Float16)p3;
            __builtin_amdgcn_wave_barrier();
            // A-frag (16x16x16): row = c, k = g*4+j
            half4v af = *(half4v*)&myp[c * 20 + g * 4];
            __builtin_amdgcn_wave_barrier();
            #pragma unroll
            for (int n = 0; n < 4; ++n) {
                half4v bv;
                #pragma unroll
                for (int j = 0; j < 4; ++j) bv[j] = (_Float16)vb[j * DHEAD + n * 16];
                o[n] = __builtin_amdgcn_mfma_f32_16x16x16f16(af, bv, o[n], 0, 0, 0);
            }
            kb += 16 * DHEAD; vb += 16 * DHEAD; mb += 16; ab += 16;
        }
    }
    // ---- out store: rows g*4+i, cols n*16+c ----
    {
        float* ob = outp + (size_t)(q0 + g * 4) * DHEAD + c;
        #pragma unroll
        for (int n = 0; n < 4; ++n) {
            #pragma unroll
            for (int i = 0; i < 4; ++i) ob[i * DHEAD + n * 16] = o[n][i];
        }
    }
}

extern "C" void kernel_launch(void* const* d_in, const int* in_sizes, int n_in,
                              void* d_out, int out_size, void* d_ws, size_t ws_size,
                              hipStream_t stream) {
    const float* q    = (const float*)d_in[0];
    const float* k    = (const float*)d_in[1];
    const float* v    = (const float*)d_in[2];
    const int*   mask = (const int*)d_in[3];
    float* out  = (float*)d_out;
    float* attn = out + (size_t)BATCH * HEADS * S_LEN * DHEAD;  // tuple: (out, attn)
    attn_flash<<<dim3(NBLK), dim3(NTHR), 0, stream>>>(q, k, v, mask, out, attn);
}

// Round 5
// 665.649 us; speedup vs baseline: 2.0079x; 2.0079x over previous
//
#include <hip/hip_runtime.h>

#define S_LEN 2048
#define DHEAD 64
#define QBLK 32
#define KBLK 64
#define NT (S_LEN / KBLK)         // 32 tiles
#define NTHR 512
#define BATCH 4
#define HEADS 16
#define NBH (BATCH * HEADS)       // 64
#define NQT (S_LEN / QBLK)        // 64
#define NBLK (NBH * NQT)          // 4096
#define NEG_BIG (-1e9f)
#define PSTR 72                   // padded f16 row stride: 144 B = 36 words (mod 32 = 4) -> <=2-way banks everywhere

typedef _Float16 half2v __attribute__((ext_vector_type(2)));
typedef _Float16 half4v __attribute__((ext_vector_type(4)));
typedef _Float16 half8v __attribute__((ext_vector_type(8)));
typedef float floatx4 __attribute__((ext_vector_type(4)));

__device__ __forceinline__ half4v cvt4(floatx4 a) {
    half4v h; h[0] = (_Float16)a[0]; h[1] = (_Float16)a[1];
    h[2] = (_Float16)a[2]; h[3] = (_Float16)a[3]; return h;
}
__device__ __forceinline__ half8v cvt8s(floatx4 a, floatx4 b, float s) {
    half8v h;
    h[0] = (_Float16)(a[0]*s); h[1] = (_Float16)(a[1]*s); h[2] = (_Float16)(a[2]*s); h[3] = (_Float16)(a[3]*s);
    h[4] = (_Float16)(b[0]*s); h[5] = (_Float16)(b[1]*s); h[6] = (_Float16)(b[2]*s); h[7] = (_Float16)(b[3]*s);
    return h;
}

__global__ __launch_bounds__(NTHR, 6)
void attn_fused(const float* __restrict__ qg, const float* __restrict__ kg,
                const float* __restrict__ vg, const int* __restrict__ maskg,
                float* __restrict__ outg, float* __restrict__ attng)
{
    __shared__ __attribute__((aligned(16))) _Float16 kb[KBLK * PSTR];   // K[key][d]   9216 B
    __shared__ __attribute__((aligned(16))) _Float16 vb[DHEAD * PSTR];  // Vt[d][key]  9216 B
    __shared__ __attribute__((aligned(16))) _Float16 pb[QBLK * PSTR];   // P[row][key] 4608 B
    __shared__ float mzb[2][QBLK][4];                                   // 1 KB

    const int tid  = threadIdx.x;
    const int lane = tid & 63;
    const int w    = tid >> 6;
    const int c    = lane & 15;
    const int g    = lane >> 4;
    const int kgrp = w & 3;       // QK: key-group / PV: d-group
    const int rh   = w >> 2;      // row-half (both phases)

    // XCD-aware swizzle: consecutive logical blocks (same head) on same XCD; 4096 % 8 == 0 -> bijective
    const int raw = blockIdx.x;
    const int lb  = (raw & 7) * (NBLK / 8) + (raw >> 3);
    const int bh  = lb >> 6;
    const int qt  = lb & 63;
    const int q0  = qt * QBLK;
    const int b   = bh >> 4;      // HEADS = 16

    const float* qp = qg + (size_t)bh * S_LEN * DHEAD;
    const float* kp = kg + (size_t)bh * S_LEN * DHEAD;
    const float* vp = vg + (size_t)bh * S_LEN * DHEAD;
    const int*   mp = maskg + (size_t)b * S_LEN * S_LEN;
    float* outp  = outg  + (size_t)bh * S_LEN * DHEAD;
    float* attnp = attng + (size_t)bh * S_LEN * S_LEN;

    // ---- staging maps ----
    const int sk_key = tid >> 4;            // 0..31 (and +32 for second slice)
    const int sk_d0  = (tid & 15) << 2;
    floatx4 kpre[2], vpre[2];

    auto loadK = [&](int t) {
        const float* base = kp + (size_t)(t * KBLK) * DHEAD + sk_d0;
        kpre[0] = *(const floatx4*)(base + sk_key * DHEAD);
        kpre[1] = *(const floatx4*)(base + (sk_key + 32) * DHEAD);
    };
    auto writeK = [&]() {
        *(half4v*)(&kb[sk_key * PSTR + sk_d0])        = cvt4(kpre[0]);
        *(half4v*)(&kb[(sk_key + 32) * PSTR + sk_d0]) = cvt4(kpre[1]);
    };
    auto loadV = [&](int t) {
        const float* base = vp + (size_t)(t * KBLK + 2 * sk_key) * DHEAD + sk_d0;
        vpre[0] = *(const floatx4*)(base);
        vpre[1] = *(const floatx4*)(base + DHEAD);
    };
    auto writeV = [&]() {
        #pragma unroll
        for (int jj = 0; jj < 4; ++jj) {
            half2v h; h[0] = (_Float16)vpre[0][jj]; h[1] = (_Float16)vpre[1][jj];
            *(half2v*)(&vb[(sk_d0 + jj) * PSTR + 2 * sk_key]) = h;
        }
    };

    // ---- Q A-frags (f16, pre-scaled 1/T): rows rh*16+c, k(d) = g*8+j (+32) ----
    half8v qf0, qf1;
    {
        const float* qb = qp + (size_t)(q0 + rh * 16 + c) * DHEAD + g * 8;
        qf0 = cvt8s(*(const floatx4*)qb,        *(const floatx4*)(qb + 4),  0.125f);
        qf1 = cvt8s(*(const floatx4*)(qb + 32), *(const floatx4*)(qb + 36), 0.125f);
    }

    const int* mrow = mp + (size_t)(q0 + rh * 16 + g * 4) * S_LEN + kgrp * 16 + c;

    // ======================= pass 1: online (m,z) =======================
    float m[4], z[4];
    #pragma unroll
    for (int i = 0; i < 4; ++i) { m[i] = -3e38f; z[i] = 0.f; }
    loadK(0);
    #pragma unroll 1
    for (int t = 0; t < NT; ++t) {
        if (t) __syncthreads();          // prev tile reads done
        writeK();
        __syncthreads();                 // writes visible
        if (t + 1 < NT) loadK(t + 1);    // T14: issue early, consume next iter
        const _Float16* krow = &kb[(kgrp * 16 + c) * PSTR];
        half8v b0 = *(const half8v*)(krow + g * 8);
        half8v b1 = *(const half8v*)(krow + 32 + g * 8);
        floatx4 acc = {0.f, 0.f, 0.f, 0.f};
        acc = __builtin_amdgcn_mfma_f32_16x16x32_f16(qf0, b0, acc, 0, 0, 0);
        acc = __builtin_amdgcn_mfma_f32_16x16x32_f16(qf1, b1, acc, 0, 0, 0);
        const int* mt = mrow + t * KBLK;
        #pragma unroll
        for (int i = 0; i < 4; ++i) {
            float x  = mt[i * S_LEN] ? acc[i] : NEG_BIG;
            float mn = fmaxf(m[i], x);
            z[i] = z[i] * __expf(m[i] - mn) + __expf(x - mn);
            m[i] = mn;
        }
    }
    // merge across the 16 c-lanes (bits 0..3 of lane)
    #pragma unroll
    for (int off = 1; off <= 8; off <<= 1) {
        #pragma unroll
        for (int i = 0; i < 4; ++i) {
            float mm = __shfl_xor(m[i], off);
            float zz = __shfl_xor(z[i], off);
            float mn = fmaxf(m[i], mm);
            z[i] = z[i] * __expf(m[i] - mn) + zz * __expf(mm - mn);
            m[i] = mn;
        }
    }
    if (c == 0) {
        #pragma unroll
        for (int i = 0; i < 4; ++i) {
            mzb[0][rh * 16 + g * 4 + i][kgrp] = m[i];
            mzb[1][rh * 16 + g * 4 + i][kgrp] = z[i];
        }
    }
    __syncthreads();
    float r_[4];
    #pragma unroll
    for (int i = 0; i < 4; ++i) {
        int row = rh * 16 + g * 4 + i;
        float M = mzb[0][row][0], Z = mzb[1][row][0];
        #pragma unroll
        for (int k2 = 1; k2 < 4; ++k2) {
            float mm = mzb[0][row][k2], zz = mzb[1][row][k2];
            float mn = fmaxf(M, mm);
            Z = Z * __expf(M - mn) + zz * __expf(mm - mn);
            M = mn;
        }
        m[i] = M; r_[i] = 1.0f / Z;
    }

    // ======================= pass 2: p, attn, PV =======================
    floatx4 o = {0.f, 0.f, 0.f, 0.f};
    const int ar = tid >> 4;               // attn-store row
    const int ak = (tid & 15) << 2;        // attn-store col base
    loadK(0); loadV(0);
    #pragma unroll 1
    for (int t = 0; t < NT; ++t) {
        __syncthreads();                   // prev tile reads (and mzb reads) done
        writeK(); writeV();
        __syncthreads();                   // staged tile visible
        if (t + 1 < NT) { loadK(t + 1); loadV(t + 1); }
        // QK^T
        const _Float16* krow = &kb[(kgrp * 16 + c) * PSTR];
        half8v b0 = *(const half8v*)(krow + g * 8);
        half8v b1 = *(const half8v*)(krow + 32 + g * 8);
        floatx4 acc = {0.f, 0.f, 0.f, 0.f};
        acc = __builtin_amdgcn_mfma_f32_16x16x32_f16(qf0, b0, acc, 0, 0, 0);
        acc = __builtin_amdgcn_mfma_f32_16x16x32_f16(qf1, b1, acc, 0, 0, 0);
        const int* mt = mrow + t * KBLK;
        #pragma unroll
        for (int i = 0; i < 4; ++i) {
            float x = mt[i * S_LEN] ? acc[i] : NEG_BIG;
            float p = __expf(x - m[i]) * r_[i];
            pb[(rh * 16 + g * 4 + i) * PSTR + kgrp * 16 + c] = (_Float16)p;
        }
        __syncthreads();                   // p visible
        // attn store: 256B fully-coalesced nontemporal float4
        {
            half4v p4 = *(const half4v*)(&pb[ar * PSTR + ak]);
            floatx4 st = {(float)p4[0], (float)p4[1], (float)p4[2], (float)p4[3]};
            __builtin_nontemporal_store(st, (floatx4*)(attnp + (size_t)(q0 + ar) * S_LEN + t * KBLK + ak));
        }
        // PV: A = P rows rh*16+c, B = Vt cols kgrp*16+c (kgrp doubles as d-group)
        const _Float16* prow = &pb[(rh * 16 + c) * PSTR];
        const _Float16* vrow = &vb[(kgrp * 16 + c) * PSTR];
        half8v a0 = *(const half8v*)(prow + g * 8);
        half8v a1 = *(const half8v*)(prow + 32 + g * 8);
        half8v v0 = *(const half8v*)(vrow + g * 8);
        half8v v1 = *(const half8v*)(vrow + 32 + g * 8);
        o = __builtin_amdgcn_mfma_f32_16x16x32_f16(a0, v0, o, 0, 0, 0);
        o = __builtin_amdgcn_mfma_f32_16x16x32_f16(a1, v1, o, 0, 0, 0);
    }
    // out: rows rh*16+g*4+i, col kgrp*16+c
    {
        float* ob = outp + (size_t)(q0 + rh * 16 + g * 4) * DHEAD + kgrp * 16 + c;
        #pragma unroll
        for (int i = 0; i < 4; ++i)
            __builtin_nontemporal_store(o[i], ob + i * DHEAD);
    }
}

extern "C" void kernel_launch(void* const* d_in, const int* in_sizes, int n_in,
                              void* d_out, int out_size, void* d_ws, size_t ws_size,
                              hipStream_t stream) {
    const float* q    = (const float*)d_in[0];
    const float* k    = (const float*)d_in[1];
    const float* v    = (const float*)d_in[2];
    const int*   mask = (const int*)d_in[3];
    float* out  = (float*)d_out;
    float* attn = out + (size_t)BATCH * HEADS * S_LEN * DHEAD;  // tuple: (out, attn)
    attn_fused<<<dim3(NBLK), dim3(NTHR), 0, stream>>>(q, k, v, mask, out, attn);
}